// Round 14
// baseline (667.417 us; speedup 1.0000x reference)
//
#include <hip/hip_runtime.h>
#include <cstdint>
#include <cstddef>

typedef unsigned short u16;
typedef __attribute__((ext_vector_type(8))) short sv8;
typedef __attribute__((ext_vector_type(4))) short sv4;
typedef __attribute__((ext_vector_type(4))) float fv4;
typedef __attribute__((ext_vector_type(8))) __bf16 bv8;

#define WAITVM(N) asm volatile("s_waitcnt vmcnt(" #N ")" ::: "memory")
#define WAITLG(N) asm volatile("s_waitcnt lgkmcnt(" #N ")" ::: "memory")
#define SB0() __builtin_amdgcn_sched_barrier(0)
#define BAR() __builtin_amdgcn_s_barrier()

__device__ __forceinline__ float b2f(u16 u) {
  union { unsigned int i; float f; } v; v.i = ((unsigned int)u) << 16; return v.f;
}
__device__ __forceinline__ u16 f2b(float f) {
  union { float f; unsigned int i; } v; v.f = f;
  unsigned int r = v.i + 0x7fffu + ((v.i >> 16) & 1u);
  return (u16)(r >> 16);
}

__device__ __forceinline__ void gload16(const u16* g, u16* l) {
  __builtin_amdgcn_global_load_lds(
      (const __attribute__((address_space(1))) void*)g,
      (__attribute__((address_space(3))) void*)l, 16, 0, 0);
}

// ---------------- f32 -> bf16 conversion (10 tensors in one launch) ----------
struct CvtArgs { const float* src[10]; u16* dst[10]; int n[10]; };

__global__ __launch_bounds__(256) void cvt_multi(CvtArgs a) {
  int t = blockIdx.y;
  const float* s = a.src[t];
  u16* d = a.dst[t];
  int n = a.n[t];
  int i4 = (blockIdx.x * 256 + threadIdx.x) * 4;
  if (i4 + 4 <= n) {
    float4 v = *(const float4*)(s + i4);
    sv4 o;
    o[0] = (short)f2b(v.x); o[1] = (short)f2b(v.y);
    o[2] = (short)f2b(v.z); o[3] = (short)f2b(v.w);
    *(sv4*)(d + i4) = o;
  }
}

// ---------------- cvt with per-column (k) scale: W' = W * g[k] ---------------
__global__ __launch_bounds__(256) void cvt_scale(
    const float* __restrict__ s, const float* __restrict__ g, u16* __restrict__ d) {
  int i4 = (blockIdx.x * 256 + threadIdx.x) * 4;   // 589824 elements, 576 blocks
  if (i4 + 4 <= 589824) {
    float4 v = *(const float4*)(s + i4);
    int k = i4 % 768;                               // row-major [768][768]
    sv4 o;
    o[0] = (short)f2b(v.x * g[k]);
    o[1] = (short)f2b(v.y * g[k + 1]);
    o[2] = (short)f2b(v.z * g[k + 2]);
    o[3] = (short)f2b(v.w * g[k + 3]);
    *(sv4*)(d + i4) = o;
  }
}

// ---------------- prep: 3 matvecs + misc, one launch -------------------------
// blocks 0..191: q0 = dec_in_w @ b_rel + dec_in_b
// blocks 192..383: b1p = l1_w @ ln1b + l1_b
// blocks 384..575: cs1 = l1_w @ ln1g
// block 576: folded biases + scalars
__global__ __launch_bounds__(256) void prep_mv(
    const float* __restrict__ dec_in_w, const float* __restrict__ dec_in_b,
    const float* __restrict__ b_rel, float* __restrict__ q0,
    const float* __restrict__ l1w, const float* __restrict__ l1b,
    const float* __restrict__ ln1g, const float* __restrict__ ln1b,
    float* __restrict__ b1p, float* __restrict__ cs1,
    const float* __restrict__ dec_out_b,
    const float* __restrict__ ln2g, const float* __restrict__ ln2b,
    const float* __restrict__ fc_w, const float* __restrict__ fc_b,
    float* __restrict__ bb, float* __restrict__ gfc, float* __restrict__ scal) {
  int blk = blockIdx.x;
  int tid = threadIdx.x, wave = tid >> 6, lane = tid & 63;
  if (blk < 576) {
    const float* wsrc; const float* vsrc; float* dst; const float* badd;
    int base;
    if (blk < 192)      { wsrc = dec_in_w; vsrc = b_rel; dst = q0;  badd = dec_in_b; base = blk; }
    else if (blk < 384) { wsrc = l1w;      vsrc = ln1b;  dst = b1p; badd = l1b;      base = blk - 192; }
    else                { wsrc = l1w;      vsrc = ln1g;  dst = cs1; badd = nullptr;  base = blk - 384; }
    int row = base * 4 + wave;
    const float* wrp = wsrc + (size_t)row * 768;
    float acc = 0.f;
    #pragma unroll
    for (int t = 0; t < 3; t++) {
      float4 wv = *(const float4*)(wrp + (t * 64 + lane) * 4);
      float4 bv = *(const float4*)(vsrc + (t * 64 + lane) * 4);
      acc += wv.x * bv.x + wv.y * bv.y + wv.z * bv.z + wv.w * bv.w;
    }
    #pragma unroll
    for (int d = 1; d <= 32; d <<= 1) acc += __shfl_xor(acc, d);
    if (lane == 0) dst[row] = acc + (badd ? badd[row] : 0.f);
  } else {
    float s1 = 0.f, s2 = 0.f;
    for (int t = tid; t < 768; t += 256) {
      bb[t] = dec_out_b[t] + b_rel[t];
      float gf = ln2g[t] * fc_w[t];
      gfc[t] = gf;
      s1 += gf; s2 += ln2b[t] * fc_w[t];
    }
    #pragma unroll
    for (int d = 1; d <= 32; d <<= 1) { s1 += __shfl_xor(s1, d); s2 += __shfl_xor(s2, d); }
    __shared__ float r1[4], r2[4];
    if (lane == 0) { r1[wave] = s1; r2[wave] = s2; }
    __syncthreads();
    if (tid == 0) {
      scal[1] = r1[0] + r1[1] + r1[2] + r1[3];
      scal[0] = r2[0] + r2[1] + r2[2] + r2[3] + fc_b[0];
    }
  }
}

// ---------------- prep: q0k[b][c] = scl * (q0_h . kh[b,k,h]) ----------------
__global__ __launch_bounds__(256) void prep_q0k(
    const float* __restrict__ q0, const u16* __restrict__ khb,
    float* __restrict__ q0k) {
  int wave = threadIdx.x >> 6, lane = threadIdx.x & 63;
  int idx = blockIdx.x * 4 + wave;
  int b = idx / 192, c = idx % 192;
  int h = (c < 96) ? 0 : 1;
  int k = (c < 96) ? c : c - 96;
  const u16* kr = khb + ((size_t)(b * 96 + k)) * 768 + h * 384;
  const float* qp = q0 + h * 384;
  float acc = 0.f;
  #pragma unroll
  for (int t = 0; t < 6; t++) {
    int d = t * 64 + lane;
    acc += qp[d] * b2f(kr[d]);
  }
  #pragma unroll
  for (int d = 1; d <= 32; d <<= 1) acc += __shfl_xor(acc, d);
  if (lane == 0) q0k[idx] = acc * 0.05103103630798287f;
}

// ---------------- stable 0/1-sort selection (coalesced + wave scan) ----------
__global__ __launch_bounds__(256) void select_pairs(
    const float* __restrict__ logits, const int* __restrict__ bm,
    int* __restrict__ idxb, int* __restrict__ encpad, int* __restrict__ zflag) {
  int b = blockIdx.x, tid = threadIdx.x;
  int wave = tid >> 6, lane = tid & 63;
  __shared__ unsigned char pos[16384];
  __shared__ int bml[128];
  __shared__ int wsum[4];
  const float* lg = logits + (size_t)b * 16384;
  if (tid < 128) bml[tid] = bm[b * 128 + tid];
  __syncthreads();
  for (int i = 0; i < 16; i++) {
    int e4 = (i * 256 + tid) * 4;
    float4 v = *(const float4*)(lg + e4);
    uchar4 o;
    {
      float sg = 1.f / (1.f + expf(-v.x));
      o.x = (!(sg < 0.5f)) && bml[e4 >> 7] && bml[e4 & 127];
      sg = 1.f / (1.f + expf(-v.y));
      o.y = (!(sg < 0.5f)) && bml[(e4 + 1) >> 7] && bml[(e4 + 1) & 127];
      sg = 1.f / (1.f + expf(-v.z));
      o.z = (!(sg < 0.5f)) && bml[(e4 + 2) >> 7] && bml[(e4 + 2) & 127];
      sg = 1.f / (1.f + expf(-v.w));
      o.w = (!(sg < 0.5f)) && bml[(e4 + 3) >> 7] && bml[(e4 + 3) & 127];
    }
    *(uchar4*)(pos + e4) = o;
  }
  __syncthreads();
  int cnt = 0;
  #pragma unroll 8
  for (int u = 0; u < 64; u++) cnt += pos[tid * 64 + u];
  int v = cnt;
  #pragma unroll
  for (int d = 1; d < 64; d <<= 1) { int o = __shfl_up(v, d); if (lane >= d) v += o; }
  if (lane == 63) wsum[wave] = v;
  __syncthreads();
  int wbase = 0;
  for (int w = 0; w < wave; w++) wbase += wsum[w];
  int mtot = wsum[0] + wsum[1] + wsum[2] + wsum[3];
  int pq = wbase + v - cnt;
  int nq = tid * 64 - pq;
  for (int u = 0; u < 64; u++) {
    int p = tid * 64 + u;
    if (pos[p]) {
      if (pq < 96) { idxb[b * 96 + pq] = p; encpad[b * 96 + pq] = 0; zflag[b * 96 + pq] = 0; }
      pq++;
    } else {
      int slot = mtot + nq;
      if (slot < 96) { idxb[b * 96 + slot] = p; encpad[b * 96 + slot] = 1; zflag[b * 96 + slot] = 1; }
      nq++;
    }
  }
  __syncthreads();
  if (tid == 0) encpad[b * 96] = 0;   // enc_pad[:,0] = False
}

// ---------------- gather pos_pairs (zeroed for fill slots) -------------------
__global__ __launch_bounds__(256) void gather_pp(
    const float* __restrict__ Af, const float* __restrict__ Cf,
    const float* __restrict__ b_rel, const int* __restrict__ idxb,
    const int* __restrict__ zflag, u16* __restrict__ PP) {
  int s = blockIdx.x, b = blockIdx.y;
  int slot = b * 96 + s;
  int p = idxb[slot];
  int z = zflag[slot];
  const float* ar = Af + ((size_t)b * 128 + (p >> 7)) * 768;
  const float* cr = Cf + ((size_t)b * 128 + (p & 127)) * 768;
  for (int c = threadIdx.x; c < 768; c += 256) {
    float v = z ? 0.f : (ar[c] + cr[c] + b_rel[c]);
    PP[(size_t)slot * 768 + c] = f2b(v);
  }
}

// ---------------- generic bf16 MFMA GEMM (small shapes) ----------------------
template<int EPI, int OUTM, int BM>
__global__ __launch_bounds__(256) void gemm_bt(
    const u16* __restrict__ Aptr, const u16* __restrict__ Wptr,
    const float* __restrict__ bias,
    void* __restrict__ out1, void* __restrict__ out2,
    const u16* __restrict__ resp, int ldr,
    int M, int N, int K, int lda, int ldw, int ldo,
    int ZH, int zbm, int bstr,
    long sAb, long sAh, long sWb, long sWh, long sOb, long sOh,
    float scale) {
  constexpr int FR = BM / 32;
  constexpr int BUF = BM * 32;
  int z = blockIdx.z;
  int zb = z / ZH, zh = z % ZH;
  const u16* A = Aptr + (size_t)zb * sAb + (size_t)zh * sAh;
  const u16* W = Wptr + (size_t)(zb & zbm) * sWb + (size_t)zh * sWh;
  const float* bz = bias ? bias + (size_t)zb * bstr : nullptr;
  size_t obase = (size_t)zb * sOb + (size_t)zh * sOh;

  int m0 = blockIdx.x * BM, n0 = blockIdx.y * BM;
  int tid = threadIdx.x;
  int wave = tid >> 6, lane = tid & 63;
  int wr = (wave >> 1) * (BM / 2), wc = (wave & 1) * (BM / 2);

  __shared__ __attribute__((aligned(16))) u16 As[4 * BUF];
  __shared__ __attribute__((aligned(16))) u16 Ws[4 * BUF];

  fv4 acc[FR][FR] = {};

  int srow = tid & (BM - 1);
  int scol = (BM == 128) ? ((tid >> 7) * 8) : ((tid >> 6) * 8);
  int ra = m0 + srow; if (ra > M - 1) ra = M - 1;
  int rw = n0 + srow; if (rw > N - 1) rw = N - 1;
  const u16* gA = A + (size_t)ra * lda + scol;
  const u16* gW = W + (size_t)rw * ldw + scol;
  int lofs = wave * 512;

  int rb = (lane >> 4) * (BM * 8) + (lane & 15) * 8;

  int nt = K >> 5;

  auto stage = [&](int tile) {
    int k0 = tile << 5;
    int cu = tile & 3;
    u16* la = As + cu * BUF + lofs;
    u16* lw = Ws + cu * BUF + lofs;
    gload16(gA + k0, la);
    gload16(gW + k0, lw);
    if (BM == 128) {
      gload16(gA + k0 + 16, la + 2048);
      gload16(gW + k0 + 16, lw + 2048);
    }
  };

  auto compute = [&](int cu) {
    const u16* Ap = As + cu * BUF;
    const u16* Wp = Ws + cu * BUF;
    bv8 af[FR], wf[FR];
    #pragma unroll
    for (int f = 0; f < FR; f++) af[f] = *(const bv8*)(Ap + rb + (wr + f * 16) * 8);
    #pragma unroll
    for (int f = 0; f < FR; f++) wf[f] = *(const bv8*)(Wp + rb + (wc + f * 16) * 8);
    __builtin_amdgcn_s_setprio(1);
    #pragma unroll
    for (int fm = 0; fm < FR; fm++)
      #pragma unroll
      for (int fn = 0; fn < FR; fn++)
        acc[fm][fn] = __builtin_amdgcn_mfma_f32_16x16x32_bf16(af[fm], wf[fn], acc[fm][fn], 0, 0, 0);
    __builtin_amdgcn_s_setprio(0);
  };

  stage(0); stage(1); stage(2);

  for (int t = 0; t < nt - 3; ++t) {
    if constexpr (BM == 128) WAITVM(8); else WAITVM(4);
    BAR();
    stage(t + 3);
    SB0();
    compute(t & 3);
  }
  { if constexpr (BM == 128) WAITVM(8); else WAITVM(4); BAR(); SB0(); compute((nt - 3) & 3); }
  { if constexpr (BM == 128) WAITVM(4); else WAITVM(2); BAR(); SB0(); compute((nt - 2) & 3); }
  { WAITVM(0); BAR(); SB0(); compute((nt - 1) & 3); }

  int lr4 = (lane >> 4) * 4, lc = lane & 15;
  #pragma unroll
  for (int fm = 0; fm < FR; fm++) {
    #pragma unroll
    for (int r = 0; r < 4; r++) {
      int row = m0 + wr + fm * 16 + lr4 + r;
      if (row >= M) continue;
      #pragma unroll
      for (int fn = 0; fn < FR; fn++) {
        int col = n0 + wc + fn * 16 + lc;
        if (col >= N) continue;
        float v = acc[fm][fn][r] * scale;
        if (bz) v += bz[col];
        if (EPI == 1) v = fmaxf(v, 0.f);
        if (EPI == 2) v += b2f(resp[(size_t)row * ldr + col]);
        size_t o = obase + (size_t)row * ldo + col;
        if (OUTM == 0) ((u16*)out1)[o] = f2b(v);
        else if (OUTM == 1) ((float*)out1)[o] = v;
        else { ((float*)out1)[o] = v; ((u16*)out2)[o] = f2b(v); }
      }
    }
  }
}

// ---------------- 256x256 GEMM v6: fused-LN epilogues ------------------------
// v5 K-loop (coalesced staging, XOR LDS, reuse-aware XCD swizzle, front-loaded
// staging). Epilogues:
//  EPI==3 (Y1): v = acc + bias + exA + exC (LDS-staged); store bf16; per-row
//               (sum, sumsq) shuffle-reduce + atomicAdd into stO (stats1).
//  EPI==4 (l1): A = raw Y1, W pre-scaled by ln1 gamma. v = r*(acc - mu*cs[col])
//               + b1p[col]; relu; store. mu,r from stA (stats1).
//  EPI==5 (l2): residual X = (b2f(resp)-mu)*r*g1[col] + b1[col];
//               v = acc + bias[col] + X; accumulate (sum, sumsq, sum gfc*v)
//               into stO (stats2); NO global store.
template<int EPI>
__global__ __launch_bounds__(512, 2) void gemm256(
    const u16* __restrict__ Aptr, const u16* __restrict__ Wptr,
    const float* __restrict__ bias, u16* __restrict__ out,
    const u16* __restrict__ resp, int ldr,
    const u16* __restrict__ exA, const u16* __restrict__ exC,
    const float* __restrict__ stA, float* __restrict__ stO,
    const float* __restrict__ vA, const float* __restrict__ vB,
    const float* __restrict__ vC,
    int K, int lda, int ldw, int ldo,
    long zA, long zW, long zO, long zR, long zE) {
  __shared__ __attribute__((aligned(16))) u16 lds[2 * 2 * 16384];  // 128 KB

  int nzz = gridDim.z;
  int lin = blockIdx.x + 64 * (blockIdx.y + 3 * blockIdx.z);
  int xcd = lin & 7;
  int s = lin >> 3;
  int grp = s / (3 * nzz);
  int rem = s - grp * (3 * nzz);
  int by = rem / nzz;
  int zz = rem - by * nzz;
  int bx = xcd + 8 * grp;

  const u16* A = Aptr + (size_t)zz * zA;
  const u16* W = Wptr + (size_t)zz * zW;
  u16* outz = out + (size_t)zz * zO;
  const u16* respz = resp + (size_t)zz * zR;
  const u16* exAz = exA + (size_t)zz * zE;
  const u16* exCz = exC + (size_t)zz * zE;
  size_t zrow = (size_t)zz * 16384;

  int m0 = bx * 256, n0 = by * 256;
  int tid = threadIdx.x;
  int wave = tid >> 6, lane = tid & 63;
  int wr = (wave >> 2) * 128;
  int wc = (wave & 3) * 64;
  int lr = lane & 15, ls = lane >> 4;
  int axor = lr & 7;

  int srow = tid >> 3;
  int schunk = (tid & 7) ^ (srow & 7);
  const u16* gA0 = A + (size_t)(m0 + srow) * lda + schunk * 8;
  const u16* gW0 = W + (size_t)(n0 + srow) * ldw + schunk * 8;
  int wofs = wave * 512;

  fv4 acc[8][4] = {};

  auto stageA = [&](int t, int q) {
    gload16(gA0 + (size_t)q * 64 * lda + t * 64,
            lds + (t & 1) * 32768 + q * 4096 + wofs);
  };
  auto stageW = [&](int t, int q) {
    gload16(gW0 + (size_t)q * 64 * ldw + t * 64,
            lds + (t & 1) * 32768 + 16384 + q * 4096 + wofs);
  };

  int TH = K >> 6;
  #pragma unroll
  for (int q = 0; q < 4; q++) stageA(0, q);
  #pragma unroll
  for (int q = 0; q < 4; q++) stageW(0, q);
  WAITVM(0);
  BAR();

  int k0o = (ls ^ axor) * 8;
  int k1o = ((ls + 4) ^ axor) * 8;

  for (int t = 0; t < TH; ++t) {
    const u16* Ab = lds + (t & 1) * 32768;
    const u16* Wb = Ab + 16384;
    bool st = (t + 1 < TH);
    bv8 af[4], wf[4];
    // phase 0
    #pragma unroll
    for (int n = 0; n < 4; n++)
      wf[n] = *(const bv8*)(Wb + (wc + n * 16 + lr) * 64 + k0o);
    #pragma unroll
    for (int f = 0; f < 4; f++)
      af[f] = *(const bv8*)(Ab + (wr + f * 16 + lr) * 64 + k0o);
    if (st) { stageA(t + 1, 0); stageA(t + 1, 1); stageA(t + 1, 2); stageA(t + 1, 3); }
    WAITLG(0); SB0();
    __builtin_amdgcn_s_setprio(1);
    #pragma unroll
    for (int f = 0; f < 4; f++)
      #pragma unroll
      for (int n = 0; n < 4; n++)
        acc[f][n] = __builtin_amdgcn_mfma_f32_16x16x32_bf16(af[f], wf[n], acc[f][n], 0, 0, 0);
    __builtin_amdgcn_s_setprio(0);
    // phase 1
    #pragma unroll
    for (int f = 0; f < 4; f++)
      af[f] = *(const bv8*)(Ab + (wr + 64 + f * 16 + lr) * 64 + k0o);
    if (st) { stageW(t + 1, 0); stageW(t + 1, 1); stageW(t + 1, 2); stageW(t + 1, 3); }
    WAITLG(0); SB0();
    __builtin_amdgcn_s_setprio(1);
    #pragma unroll
    for (int f = 0; f < 4; f++)
      #pragma unroll
      for (int n = 0; n < 4; n++)
        acc[4 + f][n] = __builtin_amdgcn_mfma_f32_16x16x32_bf16(af[f], wf[n], acc[4 + f][n], 0, 0, 0);
    __builtin_amdgcn_s_setprio(0);
    // phase 2
    #pragma unroll
    for (int n = 0; n < 4; n++)
      wf[n] = *(const bv8*)(Wb + (wc + n * 16 + lr) * 64 + k1o);
    #pragma unroll
    for (int f = 0; f < 4; f++)
      af[f] = *(const bv8*)(Ab + (wr + f * 16 + lr) * 64 + k1o);
    WAITLG(0); SB0();
    __builtin_amdgcn_s_setprio(1);
    #pragma unroll
    for (int f = 0; f < 4; f++)
      #pragma unroll
      for (int n = 0; n < 4; n++)
        acc[f][n] = __builtin_amdgcn_mfma_f32_16x16x32_bf16(af[f], wf[n], acc[f][n], 0, 0, 0);
    __builtin_amdgcn_s_setprio(0);
    // phase 3
    #pragma unroll
    for (int f = 0; f < 4; f++)
      af[f] = *(const bv8*)(Ab + (wr + 64 + f * 16 + lr) * 64 + k1o);
    WAITLG(0); SB0();
    __builtin_amdgcn_s_setprio(1);
    #pragma unroll
    for (int f = 0; f < 4; f++)
      #pragma unroll
      for (int n = 0; n < 4; n++)
        acc[4 + f][n] = __builtin_amdgcn_mfma_f32_16x16x32_bf16(af[f], wf[n], acc[4 + f][n], 0, 0, 0);
    __builtin_amdgcn_s_setprio(0);
    if (st) WAITVM(0);
    BAR();
  }

  if (EPI == 3) {
    for (int c = tid; c < 4096; c += 512) {
      int rrow = c >> 5, c8 = c & 31;
      *(sv8*)(lds + (size_t)c * 8) =
          *(const sv8*)(exCz + (size_t)rrow * 768 + n0 + c8 * 8);
    }
    if (tid < 64) {
      int rrow = tid >> 5, c8 = tid & 31;
      *(sv8*)(lds + 32768 + (size_t)tid * 8) =
          *(const sv8*)(exAz + (size_t)(bx * 2 + rrow) * 768 + n0 + c8 * 8);
    }
    __syncthreads();
  }

  int lr4 = (lane >> 4) * 4, lc = lane & 15;
  #pragma unroll
  for (int fm = 0; fm < 8; fm++) {
    #pragma unroll
    for (int r = 0; r < 4; r++) {
      int row = m0 + wr + (fm >> 2) * 64 + (fm & 3) * 16 + lr4 + r;
      float mu = 0.f, rr = 0.f;
      if (EPI == 4 || EPI == 5) {
        float s1v = stA[(zrow + row) * 2];
        float q1v = stA[(zrow + row) * 2 + 1];
        mu = s1v * (1.f / 768.f);
        rr = rsqrtf(q1v * (1.f / 768.f) - mu * mu + 1e-5f);
      }
      float sv = 0.f, qv = 0.f, gv = 0.f;
      #pragma unroll
      for (int fn = 0; fn < 4; fn++) {
        int col = n0 + wc + fn * 16 + lc;
        float a = acc[fm][fn][r];
        if (EPI == 3) {
          float v = a + bias[col]
                  + b2f(lds[32768 + (size_t)((row - m0) >> 7) * 256 + (col - n0)])
                  + b2f(lds[(size_t)(row & 127) * 256 + (col - n0)]);
          outz[(size_t)row * ldo + col] = f2b(v);
          sv += v; qv += v * v;
        } else if (EPI == 4) {
          float v = rr * (a - mu * vA[col]) + bias[col];
          v = fmaxf(v, 0.f);
          outz[(size_t)row * ldo + col] = f2b(v);
        } else {
          float xres = (b2f(respz[(size_t)row * ldr + col]) - mu) * rr * vA[col] + vB[col];
          float v = a + bias[col] + xres;
          sv += v; qv += v * v; gv += vC[col] * v;
        }
      }
      if (EPI == 3 || EPI == 5) {
        #pragma unroll
        for (int d = 1; d <= 8; d <<= 1) {
          sv += __shfl_xor(sv, d);
          qv += __shfl_xor(qv, d);
          if (EPI == 5) gv += __shfl_xor(gv, d);
        }
        if (lc == 0) {
          if (EPI == 3) {
            atomicAdd(&stO[(zrow + row) * 2], sv);
            atomicAdd(&stO[(zrow + row) * 2 + 1], qv);
          } else {
            atomicAdd(&stO[(zrow + row) * 3], sv);
            atomicAdd(&stO[(zrow + row) * 3 + 1], qv);
            atomicAdd(&stO[(zrow + row) * 3 + 2], gv);
          }
        }
      }
    }
  }
}

// ---------------- encoder self-attention (per q-row, per b,h) ----------------
__global__ __launch_bounds__(128) void enc_att(
    const u16* __restrict__ QKV, const int* __restrict__ encpad, u16* __restrict__ AO) {
  int s = blockIdx.x;
  int bh = blockIdx.y;
  int b = bh >> 1, h = bh & 1;
  int tid = threadIdx.x;
  __shared__ float q[384];
  __shared__ float sc[96];
  __shared__ float red[2];
  size_t rowq = ((size_t)b * 96 + s) * 2304;
  for (int d = tid; d < 384; d += 128) q[d] = b2f(QKV[rowq + h * 384 + d]);
  __syncthreads();
  if (tid < 96) {
    const u16* kr = QKV + ((size_t)b * 96 + tid) * 2304 + 768 + h * 384;
    float acc = 0.f;
    for (int d = 0; d < 384; d++) acc += q[d] * b2f(kr[d]);
    acc *= 0.05103103630798287f;
    if (encpad[b * 96 + tid]) acc = -1e9f;
    sc[tid] = acc;
  }
  __syncthreads();
  if (tid == 0) {
    float m = sc[0];
    for (int k = 1; k < 96; k++) m = fmaxf(m, sc[k]);
    red[0] = m;
  }
  __syncthreads();
  if (tid < 96) sc[tid] = __expf(sc[tid] - red[0]);
  __syncthreads();
  if (tid == 0) {
    float sum = 0.f;
    for (int k = 0; k < 96; k++) sum += sc[k];
    red[1] = 1.f / sum;
  }
  __syncthreads();
  float inv = red[1];
  for (int d = tid; d < 384; d += 128) {
    const u16* vb = QKV + (size_t)b * 96 * 2304 + 1536 + h * 384 + d;
    float acc = 0.f;
    for (int k = 0; k < 96; k++) acc += sc[k] * b2f(vb[(size_t)k * 2304]);
    AO[((size_t)b * 96 + s) * 768 + h * 384 + d] = f2b(acc * inv);
  }
}

// ---------------- decoder softmax (all batches; SA[i]+SC[j]+q0k) -------------
__global__ __launch_bounds__(256) void softmax_pairs(
    const float* __restrict__ SA, const float* __restrict__ SC,
    const float* __restrict__ q0k,
    const int* __restrict__ encpad, u16* __restrict__ P) {
  int wave = threadIdx.x >> 6, lane = threadIdx.x & 63;
  int bi = blockIdx.y;
  int p = blockIdx.x * 4 + wave;
  int i = p >> 7, j = p & 127;
  const float* sa = SA + ((size_t)bi * 128 + i) * 192;
  const float* sc = SC + ((size_t)bi * 128 + j) * 192;
  const float* qk = q0k + bi * 192;
  int c0 = lane * 3;
  float s0, s1, s2;
  {
    int c = c0;     int k = (c < 96) ? c : c - 96;
    s0 = encpad[bi * 96 + k] ? -1e9f : (sa[c] + sc[c] + qk[c]);
    c = c0 + 1;     k = (c < 96) ? c : c - 96;
    s1 = encpad[bi * 96 + k] ? -1e9f : (sa[c] + sc[c] + qk[c]);
    c = c0 + 2;     k = (c < 96) ? c : c - 96;
    s2 = encpad[bi * 96 + k] ? -1e9f : (sa[c] + sc[c] + qk[c]);
  }
  float m = fmaxf(s0, fmaxf(s1, s2));
  #pragma unroll
  for (int d = 1; d <= 16; d <<= 1) m = fmaxf(m, __shfl_xor(m, d));
  float e0 = __expf(s0 - m), e1 = __expf(s1 - m), e2 = __expf(s2 - m);
  float sum = e0 + e1 + e2;
  #pragma unroll
  for (int d = 1; d <= 16; d <<= 1) sum += __shfl_xor(sum, d);
  float inv = 1.f / sum;
  u16* o = P + ((size_t)bi * 16384 + p) * 192 + c0;
  o[0] = f2b(e0 * inv); o[1] = f2b(e1 * inv); o[2] = f2b(e2 * inv);
}

// ---------------- LayerNorm over rows of 768 (bf16, in-place safe) -----------
__global__ __launch_bounds__(256) void ln_rows(
    const u16* __restrict__ Y, const float* __restrict__ g,
    const float* __restrict__ bt, u16* __restrict__ X, int rows) {
  int wave = threadIdx.x >> 6, lane = threadIdx.x & 63;
  int row = blockIdx.x * 4 + wave;
  if (row >= rows) return;
  const u16* y = Y + (size_t)row * 768;
  sv8 v1 = *(const sv8*)(y + lane * 8);
  sv4 v2 = *(const sv4*)(y + 512 + lane * 4);
  float x[12];
  #pragma unroll
  for (int t = 0; t < 8; t++) x[t] = b2f((u16)v1[t]);
  #pragma unroll
  for (int t = 0; t < 4; t++) x[8 + t] = b2f((u16)v2[t]);
  float s = 0.f, q = 0.f;
  #pragma unroll
  for (int t = 0; t < 12; t++) { s += x[t]; q += x[t] * x[t]; }
  #pragma unroll
  for (int d = 1; d <= 32; d <<= 1) { s += __shfl_xor(s, d); q += __shfl_xor(q, d); }
  float mean = s * (1.f / 768.f);
  float var = q * (1.f / 768.f) - mean * mean;
  float rstd = rsqrtf(var + 1e-5f);
  u16* xo = X + (size_t)row * 768;
  sv8 w1; sv4 w2;
  #pragma unroll
  for (int t = 0; t < 8; t++) {
    int c = lane * 8 + t;
    w1[t] = (short)f2b((x[t] - mean) * rstd * g[c] + bt[c]);
  }
  #pragma unroll
  for (int t = 0; t < 4; t++) {
    int c = 512 + lane * 4 + t;
    w2[t] = (short)f2b((x[8 + t] - mean) * rstd * g[c] + bt[c]);
  }
  *(sv8*)(xo + lane * 8) = w1;
  *(sv4*)(xo + 512 + lane * 4) = w2;
}

// ---------------- finish: stats2 -> output -----------------------------------
__global__ __launch_bounds__(256) void finish_rows(
    const float* __restrict__ st2, const float* __restrict__ scal,
    float* __restrict__ out, int rows) {
  int row = blockIdx.x * 256 + threadIdx.x;
  if (row >= rows) return;
  float s = st2[(size_t)row * 3];
  float q = st2[(size_t)row * 3 + 1];
  float sg = st2[(size_t)row * 3 + 2];
  float mean = s * (1.f / 768.f);
  float var = q * (1.f / 768.f) - mean * mean;
  float rstd = rsqrtf(var + 1e-5f);
  out[row] = rstd * (sg - mean * scal[1]) + scal[0];
}

// =============================== host ========================================
extern "C" void kernel_launch(void* const* d_in, const int* in_sizes, int n_in,
                              void* d_out, int out_size, void* d_ws, size_t ws_size,
                              hipStream_t stream) {
  (void)in_sizes; (void)n_in; (void)out_size;
  const float* hs        = (const float*)d_in[0];
  const float* logits    = (const float*)d_in[1];
  const int*   bmask     = (const int*)d_in[2];
  const float* W_rel     = (const float*)d_in[3];
  const float* b_rel     = (const float*)d_in[4];
  const float* enc_in_w  = (const float*)d_in[5];
  const float* enc_in_b  = (const float*)d_in[6];
  const float* enc_out_w = (const float*)d_in[7];
  const float* enc_out_b = (const float*)d_in[8];
  const float* enc_l1_w  = (const float*)d_in[9];
  const float* enc_l1_b  = (const float*)d_in[10];
  const float* enc_l2_w  = (const float*)d_in[11];
  const float* enc_l2_b  = (const float*)d_in[12];
  const float* enc_ln1_g = (const float*)d_in[13];
  const float* enc_ln1_b = (const float*)d_in[14];
  const float* enc_ln2_g = (const float*)d_in[15];
  const float* enc_ln2_b = (const float*)d_in[16];
  const float* dec_in_w  = (const float*)d_in[17];
  const float* dec_in_b  = (const float*)d_in[18];
  const float* dec_out_w = (const float*)d_in[19];
  const float* dec_out_b = (const float*)d_in[20];
  const float* dec_l1_w  = (const float*)d_in[21];
  const float* dec_l1_b  = (const float*)d_in[22];
  const float* dec_l2_w  = (const float*)d_in[23];
  const float* dec_l2_b  = (const float*)d_in[24];
  const float* dec_ln1_g = (const float*)d_in[25];
  const float* dec_ln1_b = (const float*)d_in[26];
  const float* dec_ln2_g = (const float*)d_in[27];
  const float* dec_ln2_b = (const float*)d_in[28];
  const float* fc_w      = (const float*)d_in[29];
  const float* fc_b      = (const float*)d_in[30];

  char* base = (char*)d_ws;
  size_t off = 0;
  auto alloc = [&](size_t bytes) -> void* {
    size_t o = (off + 255) & ~(size_t)255;
    off = o + bytes;
    return (void*)(base + o);
  };

  u16* hsb   = (u16*)alloc((size_t)393216 * 2);
  u16* wrelb = (u16*)alloc((size_t)1179648 * 2);
  u16* eiwb  = (u16*)alloc((size_t)1769472 * 2);
  u16* eowb  = (u16*)alloc((size_t)589824 * 2);
  u16* el1b  = (u16*)alloc((size_t)589824 * 2);
  u16* el2b  = (u16*)alloc((size_t)589824 * 2);
  u16* diwb  = (u16*)alloc((size_t)1769472 * 2);
  u16* dowb  = (u16*)alloc((size_t)589824 * 2);
  u16* dl1b  = (u16*)alloc((size_t)589824 * 2);   // scaled by ln1 gamma
  u16* dl2b  = (u16*)alloc((size_t)589824 * 2);
  float* Af  = (float*)alloc((size_t)786432 * 4);
  float* Cf  = Af + 393216;
  u16* ACb   = (u16*)alloc((size_t)786432 * 2);
  float* q0  = (float*)alloc(768 * 4);
  float* q0k = (float*)alloc(768 * 4);
  float* bbv = (float*)alloc(768 * 4);
  float* gfc = (float*)alloc(768 * 4);
  float* b1p = (float*)alloc(768 * 4);
  float* cs1 = (float*)alloc(768 * 4);
  float* scal = (float*)alloc(4 * 4);
  int* idxb   = (int*)alloc(384 * 4);
  int* encpadb = (int*)alloc(384 * 4);
  int* zflagb  = (int*)alloc(384 * 4);
  u16* PPb   = (u16*)alloc((size_t)294912 * 2);
  u16* QKVe  = (u16*)alloc((size_t)884736 * 2);
  u16* AOe   = (u16*)alloc((size_t)294912 * 2);
  u16* Ye    = (u16*)alloc((size_t)294912 * 2);
  u16* Xe    = (u16*)alloc((size_t)294912 * 2);
  u16* He    = (u16*)alloc((size_t)294912 * 2);
  u16* Y2e   = (u16*)alloc((size_t)294912 * 2);
  u16* patternsb = (u16*)alloc((size_t)294912 * 2);
  u16* khb   = (u16*)alloc((size_t)294912 * 2);
  u16* vhb   = (u16*)alloc((size_t)294912 * 2);
  u16* AqCqb = (u16*)alloc((size_t)786432 * 2);
  float* SASCf = (float*)alloc((size_t)196608 * 4);
  u16* VOTb  = (u16*)alloc((size_t)589824 * 2);
  float* stats1 = (float*)alloc((size_t)65536 * 2 * 4);  // per-row (s, q) of Y1
  float* stats2 = (float*)alloc((size_t)65536 * 3 * 4);  // per-row (s, q, sg)
  size_t statsBytes = (size_t)((char*)(stats2 + 65536 * 3) - (char*)stats1);
  u16* Pb    = (u16*)alloc((size_t)12582912 * 2);        // 4 x 16384 x 192

  const size_t ACT1 = (size_t)12582912 * 2;
  size_t fixed = (off + 255) & ~(size_t)255;
  int NB = 1;
  if (fixed + 2 * 4 * ACT1 + 4096 <= ws_size) NB = 4;
  else if (fixed + 2 * 2 * ACT1 + 4096 <= ws_size) NB = 2;
  u16* Y1buf = (u16*)alloc((size_t)NB * 12582912 * 2);
  u16* H1buf = (u16*)alloc((size_t)NB * 12582912 * 2);

  CvtArgs ca{};
  int ci = 0;
  auto addc = [&](const float* s, u16* d, int n) { ca.src[ci] = s; ca.dst[ci] = d; ca.n[ci] = n; ci++; };
  addc(hs, hsb, 393216);        addc(W_rel, wrelb, 1179648);
  addc(enc_in_w, eiwb, 1769472); addc(enc_out_w, eowb, 589824);
  addc(enc_l1_w, el1b, 589824);  addc(enc_l2_w, el2b, 589824);
  addc(dec_in_w, diwb, 1769472); addc(dec_out_w, dowb, 589824);
  addc(dec_l2_w, dl2b, 589824);
  ca.src[9] = nullptr; ca.dst[9] = nullptr; ca.n[9] = 0;
  cvt_multi<<<dim3(1728, 10, 1), 256, 0, stream>>>(ca);
  cvt_scale<<<576, 256, 0, stream>>>(dec_l1_w, dec_ln1_g, dl1b);

  prep_mv<<<577, 256, 0, stream>>>(dec_in_w, dec_in_b, b_rel, q0,
      dec_l1_w, dec_l1_b, dec_ln1_g, dec_ln1_b, b1p, cs1,
      dec_out_b, dec_ln2_g, dec_ln2_b, fc_w, fc_b, bbv, gfc, scal);
  select_pairs<<<dim3(4, 1, 1), 256, 0, stream>>>(logits, bmask, idxb, encpadb, zflagb);

  gemm_bt<0, 2, 64><<<dim3(8, 12, 2), 256, 0, stream>>>(hsb, wrelb, nullptr, Af, ACb,
      nullptr, 0, 512, 768, 768, 768, 1536, 768,
      1, -1, 0, 0, 0, 768, 0, 393216, 0, 1.f);

  gather_pp<<<dim3(96, 4, 1), 256, 0, stream>>>(Af, Cf, b_rel, idxb, zflagb, PPb);

  gemm_bt<0, 0, 64><<<dim3(6, 36, 1), 256, 0, stream>>>(PPb, eiwb, enc_in_b, QKVe, nullptr,
      nullptr, 0, 384, 2304, 768, 768, 768, 2304,
      1, -1, 0, 0, 0, 0, 0, 0, 0, 1.f);
  enc_att<<<dim3(96, 8, 1), 128, 0, stream>>>(QKVe, encpadb, AOe);
  gemm_bt<2, 0, 64><<<dim3(6, 12, 1), 256, 0, stream>>>(AOe, eowb, enc_out_b, Ye, nullptr,
      PPb, 768, 384, 768, 768, 768, 768, 768,
      1, -1, 0, 0, 0, 0, 0, 0, 0, 1.f);
  ln_rows<<<96, 256, 0, stream>>>(Ye, enc_ln1_g, enc_ln1_b, Xe, 384);
  gemm_bt<1, 0, 64><<<dim3(6, 12, 1), 256, 0, stream>>>(Xe, el1b, enc_l1_b, He, nullptr,
      nullptr, 0, 384, 768, 768, 768, 768, 768,
      1, -1, 0, 0, 0, 0, 0, 0, 0, 1.f);
  gemm_bt<2, 0, 64><<<dim3(6, 12, 1), 256, 0, stream>>>(He, el2b, enc_l2_b, Y2e, nullptr,
      Xe, 768, 384, 768, 768, 768, 768, 768,
      1, -1, 0, 0, 0, 0, 0, 0, 0, 1.f);
  ln_rows<<<96, 256, 0, stream>>>(Y2e, enc_ln2_g, enc_ln2_b, patternsb, 384);

  gemm_bt<0, 0, 64><<<dim3(6, 12, 2), 256, 0, stream>>>(patternsb, diwb + (size_t)768 * 768,
      dec_in_b + 768, khb, nullptr, nullptr, 0,
      384, 768, 768, 768, 768, 768,
      1, -1, 768, 0, 0, 589824, 0, 294912, 0, 1.f);
  prep_q0k<<<192, 256, 0, stream>>>(q0, khb, q0k);
  gemm_bt<0, 0, 64><<<dim3(16, 12, 1), 256, 0, stream>>>(ACb, diwb, nullptr, AqCqb, nullptr,
      nullptr, 0, 1024, 768, 768, 768, 768, 768,
      1, -1, 0, 0, 0, 0, 0, 0, 0, 1.f);
  const float scl = 0.05103103630798287f; // 1/sqrt(384)
  gemm_bt<0, 1, 64><<<dim3(2, 2, 16), 256, 0, stream>>>(AqCqb, khb, nullptr, SASCf, nullptr,
      nullptr, 0, 128, 96, 384, 768, 768, 192,
      2, 3, 0, 98304, 384, 73728, 384, 24576, 96, scl);
  gemm_bt<0, 0, 64><<<dim3(12, 2, 8), 256, 0, stream>>>(dowb, vhb, nullptr, VOTb, nullptr,
      nullptr, 0, 768, 96, 384, 768, 768, 192,
      2, -1, 0, 0, 384, 73728, 384, 147456, 96, 1.f);

  softmax_pairs<<<dim3(4096, 4), 256, 0, stream>>>(SASCf, SASCf + 98304, q0k, encpadb, Pb);
  hipMemsetAsync(stats1, 0, statsBytes, stream);

  const long PB_B = 3145728, VOT_B = 147456, ACT_B = 12582912;
  const long EXU_B = 98304;
  for (int g = 0; g < 4; g += NB) {
    // Y1 = P @ VOT^T + bb + exA + exC ; stats1 += (sum, sumsq)
    gemm256<3><<<dim3(64, 3, NB), 512, 0, stream>>>(
        Pb + (size_t)g * PB_B, VOTb + (size_t)g * VOT_B, bbv, Y1buf,
        Y1buf, 0,
        ACb + (size_t)g * EXU_B,
        ACb + 393216 + (size_t)g * EXU_B,
        nullptr, stats1 + (size_t)g * 16384 * 2,
        nullptr, nullptr, nullptr,
        192, 192, 192, 768, PB_B, VOT_B, ACT_B, 0, EXU_B);
    // H1 = relu(r*(Y1raw @ (W1*g)^T - mu*cs1) + b1p)
    gemm256<4><<<dim3(64, 3, NB), 512, 0, stream>>>(
        Y1buf, dl1b, b1p, H1buf,
        H1buf, 0, ACb, ACb,
        stats1 + (size_t)g * 16384 * 2, nullptr,
        cs1, nullptr, nullptr,
        768, 768, 768, 768, ACT_B, 0, ACT_B, 0, 0);
    // v = H1 @ W2^T + b2 + ln1(Y1raw) ; stats2 += (sum, sumsq, sum gfc*v)
    gemm256<5><<<dim3(64, 3, NB), 512, 0, stream>>>(
        H1buf, dl2b, dec_l2_b, Y1buf,
        Y1buf, 768, ACb, ACb,
        stats1 + (size_t)g * 16384 * 2, stats2 + (size_t)g * 16384 * 3,
        dec_ln1_g, dec_ln1_b, gfc,
        768, 768, 768, 768, ACT_B, 0, ACT_B, ACT_B, 0);
  }
  finish_rows<<<256, 256, 0, stream>>>(stats2, scal, (float*)d_out, 65536);
}

// Round 15
// 500.140 us; speedup vs baseline: 1.3345x; 1.3345x over previous
//
#include <hip/hip_runtime.h>
#include <cstdint>
#include <cstddef>

typedef unsigned short u16;
typedef __attribute__((ext_vector_type(8))) short sv8;
typedef __attribute__((ext_vector_type(4))) short sv4;
typedef __attribute__((ext_vector_type(4))) float fv4;
typedef __attribute__((ext_vector_type(8))) __bf16 bv8;

#define WAITVM(N) asm volatile("s_waitcnt vmcnt(" #N ")" ::: "memory")
#define WAITLG(N) asm volatile("s_waitcnt lgkmcnt(" #N ")" ::: "memory")
#define SB0() __builtin_amdgcn_sched_barrier(0)
#define BAR() __builtin_amdgcn_s_barrier()

__device__ __forceinline__ float b2f(u16 u) {
  union { unsigned int i; float f; } v; v.i = ((unsigned int)u) << 16; return v.f;
}
__device__ __forceinline__ u16 f2b(float f) {
  union { float f; unsigned int i; } v; v.f = f;
  unsigned int r = v.i + 0x7fffu + ((v.i >> 16) & 1u);
  return (u16)(r >> 16);
}

__device__ __forceinline__ void gload16(const u16* g, u16* l) {
  __builtin_amdgcn_global_load_lds(
      (const __attribute__((address_space(1))) void*)g,
      (__attribute__((address_space(3))) void*)l, 16, 0, 0);
}

// ---------------- f32 -> bf16 conversion (10 tensors in one launch) ----------
struct CvtArgs { const float* src[10]; u16* dst[10]; int n[10]; };

__global__ __launch_bounds__(256) void cvt_multi(CvtArgs a) {
  int t = blockIdx.y;
  const float* s = a.src[t];
  u16* d = a.dst[t];
  int n = a.n[t];
  int i4 = (blockIdx.x * 256 + threadIdx.x) * 4;
  if (i4 + 4 <= n) {
    float4 v = *(const float4*)(s + i4);
    sv4 o;
    o[0] = (short)f2b(v.x); o[1] = (short)f2b(v.y);
    o[2] = (short)f2b(v.z); o[3] = (short)f2b(v.w);
    *(sv4*)(d + i4) = o;
  }
}

// ---------------- prep: q0 matvec (wave per row) -----------------------------
__global__ __launch_bounds__(256) void prep_q0(
    const float* __restrict__ dec_in_w, const float* __restrict__ dec_in_b,
    const float* __restrict__ b_rel, float* __restrict__ q0) {
  int wave = threadIdx.x >> 6, lane = threadIdx.x & 63;
  int row = blockIdx.x * 4 + wave;
  const float* wrp = dec_in_w + (size_t)row * 768;
  float acc = 0.f;
  #pragma unroll
  for (int t = 0; t < 3; t++) {
    float4 wv = *(const float4*)(wrp + (t * 64 + lane) * 4);
    float4 bv = *(const float4*)(b_rel + (t * 64 + lane) * 4);
    acc += wv.x * bv.x + wv.y * bv.y + wv.z * bv.z + wv.w * bv.w;
  }
  #pragma unroll
  for (int d = 1; d <= 32; d <<= 1) acc += __shfl_xor(acc, d);
  if (lane == 0) q0[row] = acc + dec_in_b[row];
}

// ---------------- prep: q0k[b][c] = scl * (q0_h . kh[b,k,h]) ----------------
__global__ __launch_bounds__(256) void prep_q0k(
    const float* __restrict__ q0, const u16* __restrict__ khb,
    float* __restrict__ q0k) {
  int wave = threadIdx.x >> 6, lane = threadIdx.x & 63;
  int idx = blockIdx.x * 4 + wave;        // 0..767 over (b,c)
  int b = idx / 192, c = idx % 192;
  int h = (c < 96) ? 0 : 1;
  int k = (c < 96) ? c : c - 96;
  const u16* kr = khb + ((size_t)(b * 96 + k)) * 768 + h * 384;
  const float* qp = q0 + h * 384;
  float acc = 0.f;
  #pragma unroll
  for (int t = 0; t < 6; t++) {
    int d = t * 64 + lane;
    acc += qp[d] * b2f(kr[d]);
  }
  #pragma unroll
  for (int d = 1; d <= 32; d <<= 1) acc += __shfl_xor(acc, d);
  if (lane == 0) q0k[idx] = acc * 0.05103103630798287f;
}

// ---------------- prep: folded biases + scalars ------------------------------
__global__ __launch_bounds__(256) void prep_misc(
    const float* __restrict__ dec_out_b, const float* __restrict__ b_rel,
    const float* __restrict__ ln2g, const float* __restrict__ ln2b,
    const float* __restrict__ fc_w, const float* __restrict__ fc_b,
    float* __restrict__ bb, float* __restrict__ gfc, float* __restrict__ scal) {
  int tid = threadIdx.x;
  int wave = tid >> 6, lane = tid & 63;
  float s1 = 0.f, s2 = 0.f;
  for (int t = tid; t < 768; t += 256) {
    bb[t] = dec_out_b[t] + b_rel[t];
    float gf = ln2g[t] * fc_w[t];
    gfc[t] = gf;
    s1 += gf; s2 += ln2b[t] * fc_w[t];
  }
  #pragma unroll
  for (int d = 1; d <= 32; d <<= 1) { s1 += __shfl_xor(s1, d); s2 += __shfl_xor(s2, d); }
  __shared__ float r1[4], r2[4];
  if (lane == 0) { r1[wave] = s1; r2[wave] = s2; }
  __syncthreads();
  if (tid == 0) {
    float a = r1[0] + r1[1] + r1[2] + r1[3];
    float c = r2[0] + r2[1] + r2[2] + r2[3];
    scal[1] = a;
    scal[0] = c + fc_b[0];
  }
}

// ---------------- stable 0/1-sort selection (coalesced + wave scan) ----------
__global__ __launch_bounds__(256) void select_pairs(
    const float* __restrict__ logits, const int* __restrict__ bm,
    int* __restrict__ idxb, int* __restrict__ encpad, int* __restrict__ zflag) {
  int b = blockIdx.x, tid = threadIdx.x;
  int wave = tid >> 6, lane = tid & 63;
  __shared__ unsigned char pos[16384];
  __shared__ int bml[128];
  __shared__ int wsum[4];
  const float* lg = logits + (size_t)b * 16384;
  if (tid < 128) bml[tid] = bm[b * 128 + tid];
  __syncthreads();
  for (int i = 0; i < 16; i++) {
    int e4 = (i * 256 + tid) * 4;
    float4 v = *(const float4*)(lg + e4);
    uchar4 o;
    {
      float sg = 1.f / (1.f + expf(-v.x));
      o.x = (!(sg < 0.5f)) && bml[e4 >> 7] && bml[e4 & 127];
      sg = 1.f / (1.f + expf(-v.y));
      o.y = (!(sg < 0.5f)) && bml[(e4 + 1) >> 7] && bml[(e4 + 1) & 127];
      sg = 1.f / (1.f + expf(-v.z));
      o.z = (!(sg < 0.5f)) && bml[(e4 + 2) >> 7] && bml[(e4 + 2) & 127];
      sg = 1.f / (1.f + expf(-v.w));
      o.w = (!(sg < 0.5f)) && bml[(e4 + 3) >> 7] && bml[(e4 + 3) & 127];
    }
    *(uchar4*)(pos + e4) = o;
  }
  __syncthreads();
  int cnt = 0;
  #pragma unroll 8
  for (int u = 0; u < 64; u++) cnt += pos[tid * 64 + u];
  int v = cnt;
  #pragma unroll
  for (int d = 1; d < 64; d <<= 1) { int o = __shfl_up(v, d); if (lane >= d) v += o; }
  if (lane == 63) wsum[wave] = v;
  __syncthreads();
  int wbase = 0;
  for (int w = 0; w < wave; w++) wbase += wsum[w];
  int mtot = wsum[0] + wsum[1] + wsum[2] + wsum[3];
  int pq = wbase + v - cnt;
  int nq = tid * 64 - pq;
  for (int u = 0; u < 64; u++) {
    int p = tid * 64 + u;
    if (pos[p]) {
      if (pq < 96) { idxb[b * 96 + pq] = p; encpad[b * 96 + pq] = 0; zflag[b * 96 + pq] = 0; }
      pq++;
    } else {
      int slot = mtot + nq;
      if (slot < 96) { idxb[b * 96 + slot] = p; encpad[b * 96 + slot] = 1; zflag[b * 96 + slot] = 1; }
      nq++;
    }
  }
  __syncthreads();
  if (tid == 0) encpad[b * 96] = 0;   // enc_pad[:,0] = False
}

// ---------------- gather pos_pairs (zeroed for fill slots) -------------------
__global__ __launch_bounds__(256) void gather_pp(
    const float* __restrict__ Af, const float* __restrict__ Cf,
    const float* __restrict__ b_rel, const int* __restrict__ idxb,
    const int* __restrict__ zflag, u16* __restrict__ PP) {
  int s = blockIdx.x, b = blockIdx.y;
  int slot = b * 96 + s;
  int p = idxb[slot];
  int z = zflag[slot];
  const float* ar = Af + ((size_t)b * 128 + (p >> 7)) * 768;
  const float* cr = Cf + ((size_t)b * 128 + (p & 127)) * 768;
  for (int c = threadIdx.x; c < 768; c += 256) {
    float v = z ? 0.f : (ar[c] + cr[c] + b_rel[c]);
    PP[(size_t)slot * 768 + c] = f2b(v);
  }
}

// ---------------- generic bf16 MFMA GEMM (small shapes) ----------------------
// 4-deep counted-vmcnt pipeline. EPI: 0=none,1=relu,2=+resid. OUTM: 0/1/2.
template<int EPI, int OUTM, int BM>
__global__ __launch_bounds__(256) void gemm_bt(
    const u16* __restrict__ Aptr, const u16* __restrict__ Wptr,
    const float* __restrict__ bias,
    void* __restrict__ out1, void* __restrict__ out2,
    const u16* __restrict__ resp, int ldr,
    int M, int N, int K, int lda, int ldw, int ldo,
    int ZH, int zbm, int bstr,
    long sAb, long sAh, long sWb, long sWh, long sOb, long sOh,
    float scale) {
  constexpr int FR = BM / 32;
  constexpr int BUF = BM * 32;
  int z = blockIdx.z;
  int zb = z / ZH, zh = z % ZH;
  const u16* A = Aptr + (size_t)zb * sAb + (size_t)zh * sAh;
  const u16* W = Wptr + (size_t)(zb & zbm) * sWb + (size_t)zh * sWh;
  const float* bz = bias ? bias + (size_t)zb * bstr : nullptr;
  size_t obase = (size_t)zb * sOb + (size_t)zh * sOh;

  int m0 = blockIdx.x * BM, n0 = blockIdx.y * BM;
  int tid = threadIdx.x;
  int wave = tid >> 6, lane = tid & 63;
  int wr = (wave >> 1) * (BM / 2), wc = (wave & 1) * (BM / 2);

  __shared__ __attribute__((aligned(16))) u16 As[4 * BUF];
  __shared__ __attribute__((aligned(16))) u16 Ws[4 * BUF];

  fv4 acc[FR][FR] = {};

  int srow = tid & (BM - 1);
  int scol = (BM == 128) ? ((tid >> 7) * 8) : ((tid >> 6) * 8);
  int ra = m0 + srow; if (ra > M - 1) ra = M - 1;
  int rw = n0 + srow; if (rw > N - 1) rw = N - 1;
  const u16* gA = A + (size_t)ra * lda + scol;
  const u16* gW = W + (size_t)rw * ldw + scol;
  int lofs = wave * 512;

  int rb = (lane >> 4) * (BM * 8) + (lane & 15) * 8;

  int nt = K >> 5;                    // call sites: nt >= 12

  auto stage = [&](int tile) {
    int k0 = tile << 5;
    int cu = tile & 3;
    u16* la = As + cu * BUF + lofs;
    u16* lw = Ws + cu * BUF + lofs;
    gload16(gA + k0, la);
    gload16(gW + k0, lw);
    if (BM == 128) {
      gload16(gA + k0 + 16, la + 2048);
      gload16(gW + k0 + 16, lw + 2048);
    }
  };

  auto compute = [&](int cu) {
    const u16* Ap = As + cu * BUF;
    const u16* Wp = Ws + cu * BUF;
    bv8 af[FR], wf[FR];
    #pragma unroll
    for (int f = 0; f < FR; f++) af[f] = *(const bv8*)(Ap + rb + (wr + f * 16) * 8);
    #pragma unroll
    for (int f = 0; f < FR; f++) wf[f] = *(const bv8*)(Wp + rb + (wc + f * 16) * 8);
    __builtin_amdgcn_s_setprio(1);
    #pragma unroll
    for (int fm = 0; fm < FR; fm++)
      #pragma unroll
      for (int fn = 0; fn < FR; fn++)
        acc[fm][fn] = __builtin_amdgcn_mfma_f32_16x16x32_bf16(af[fm], wf[fn], acc[fm][fn], 0, 0, 0);
    __builtin_amdgcn_s_setprio(0);
  };

  stage(0); stage(1); stage(2);

  for (int t = 0; t < nt - 3; ++t) {
    if constexpr (BM == 128) WAITVM(8); else WAITVM(4);
    BAR();
    stage(t + 3);
    SB0();
    compute(t & 3);
  }
  { if constexpr (BM == 128) WAITVM(8); else WAITVM(4); BAR(); SB0(); compute((nt - 3) & 3); }
  { if constexpr (BM == 128) WAITVM(4); else WAITVM(2); BAR(); SB0(); compute((nt - 2) & 3); }
  { WAITVM(0); BAR(); SB0(); compute((nt - 1) & 3); }

  int lr4 = (lane >> 4) * 4, lc = lane & 15;
  #pragma unroll
  for (int fm = 0; fm < FR; fm++) {
    #pragma unroll
    for (int r = 0; r < 4; r++) {
      int row = m0 + wr + fm * 16 + lr4 + r;
      if (row >= M) continue;
      #pragma unroll
      for (int fn = 0; fn < FR; fn++) {
        int col = n0 + wc + fn * 16 + lc;
        if (col >= N) continue;
        float v = acc[fm][fn][r] * scale;
        if (bz) v += bz[col];
        if (EPI == 1) v = fmaxf(v, 0.f);
        if (EPI == 2) v += b2f(resp[(size_t)row * ldr + col]);
        size_t o = obase + (size_t)row * ldo + col;
        if (OUTM == 0) ((u16*)out1)[o] = f2b(v);
        else if (OUTM == 1) ((float*)out1)[o] = v;
        else { ((float*)out1)[o] = v; ((u16*)out2)[o] = f2b(v); }
      }
    }
  }
}

// ---------------- 256x256 GEMM v5: early-staged boundary ---------------------
// v3 structure (reuse-aware XCD swizzle, coalesced staging, XOR LDS, LDS
// epilogue for EPI3) with ALL 8 stage issues front-loaded into phases 0-1.
template<int EPI>
__global__ __launch_bounds__(512, 2) void gemm256(
    const u16* __restrict__ Aptr, const u16* __restrict__ Wptr,
    const float* __restrict__ bias, u16* __restrict__ out,
    const u16* __restrict__ resp, int ldr,
    const u16* __restrict__ exA, const u16* __restrict__ exC,
    int K, int lda, int ldw, int ldo,
    long zA, long zW, long zO, long zR, long zE) {
  __shared__ __attribute__((aligned(16))) u16 lds[2 * 2 * 16384];  // 128 KB

  int nzz = gridDim.z;
  int lin = blockIdx.x + 64 * (blockIdx.y + 3 * blockIdx.z);
  int xcd = lin & 7;
  int s = lin >> 3;
  int grp = s / (3 * nzz);
  int rem = s - grp * (3 * nzz);
  int by = rem / nzz;
  int zz = rem - by * nzz;
  int bx = xcd + 8 * grp;

  const u16* A = Aptr + (size_t)zz * zA;
  const u16* W = Wptr + (size_t)zz * zW;
  u16* outz = out + (size_t)zz * zO;
  const u16* respz = resp + (size_t)zz * zR;
  const u16* exAz = exA + (size_t)zz * zE;
  const u16* exCz = exC + (size_t)zz * zE;

  int m0 = bx * 256, n0 = by * 256;
  int tid = threadIdx.x;
  int wave = tid >> 6, lane = tid & 63;
  int wr = (wave >> 2) * 128;
  int wc = (wave & 3) * 64;
  int lr = lane & 15, ls = lane >> 4;
  int axor = lr & 7;

  int srow = tid >> 3;
  int schunk = (tid & 7) ^ (srow & 7);
  const u16* gA0 = A + (size_t)(m0 + srow) * lda + schunk * 8;
  const u16* gW0 = W + (size_t)(n0 + srow) * ldw + schunk * 8;
  int wofs = wave * 512;

  fv4 acc[8][4] = {};

  auto stageA = [&](int t, int q) {
    gload16(gA0 + (size_t)q * 64 * lda + t * 64,
            lds + (t & 1) * 32768 + q * 4096 + wofs);
  };
  auto stageW = [&](int t, int q) {
    gload16(gW0 + (size_t)q * 64 * ldw + t * 64,
            lds + (t & 1) * 32768 + 16384 + q * 4096 + wofs);
  };

  int TH = K >> 6;
  #pragma unroll
  for (int q = 0; q < 4; q++) stageA(0, q);
  #pragma unroll
  for (int q = 0; q < 4; q++) stageW(0, q);
  WAITVM(0);
  BAR();

  int k0o = (ls ^ axor) * 8;
  int k1o = ((ls + 4) ^ axor) * 8;

  for (int t = 0; t < TH; ++t) {
    const u16* Ab = lds + (t & 1) * 32768;
    const u16* Wb = Ab + 16384;
    bool st = (t + 1 < TH);
    bv8 af[4], wf[4];
    // ---- phase 0: (mh0, kh0); issue all 4 A-stages for t+1 ----
    #pragma unroll
    for (int n = 0; n < 4; n++)
      wf[n] = *(const bv8*)(Wb + (wc + n * 16 + lr) * 64 + k0o);
    #pragma unroll
    for (int f = 0; f < 4; f++)
      af[f] = *(const bv8*)(Ab + (wr + f * 16 + lr) * 64 + k0o);
    if (st) { stageA(t + 1, 0); stageA(t + 1, 1); stageA(t + 1, 2); stageA(t + 1, 3); }
    WAITLG(0); SB0();
    __builtin_amdgcn_s_setprio(1);
    #pragma unroll
    for (int f = 0; f < 4; f++)
      #pragma unroll
      for (int n = 0; n < 4; n++)
        acc[f][n] = __builtin_amdgcn_mfma_f32_16x16x32_bf16(af[f], wf[n], acc[f][n], 0, 0, 0);
    __builtin_amdgcn_s_setprio(0);
    // ---- phase 1: (mh1, kh0); issue all 4 W-stages for t+1 ----
    #pragma unroll
    for (int f = 0; f < 4; f++)
      af[f] = *(const bv8*)(Ab + (wr + 64 + f * 16 + lr) * 64 + k0o);
    if (st) { stageW(t + 1, 0); stageW(t + 1, 1); stageW(t + 1, 2); stageW(t + 1, 3); }
    WAITLG(0); SB0();
    __builtin_amdgcn_s_setprio(1);
    #pragma unroll
    for (int f = 0; f < 4; f++)
      #pragma unroll
      for (int n = 0; n < 4; n++)
        acc[4 + f][n] = __builtin_amdgcn_mfma_f32_16x16x32_bf16(af[f], wf[n], acc[4 + f][n], 0, 0, 0);
    __builtin_amdgcn_s_setprio(0);
    // ---- phase 2: (mh0, kh1) ----
    #pragma unroll
    for (int n = 0; n < 4; n++)
      wf[n] = *(const bv8*)(Wb + (wc + n * 16 + lr) * 64 + k1o);
    #pragma unroll
    for (int f = 0; f < 4; f++)
      af[f] = *(const bv8*)(Ab + (wr + f * 16 + lr) * 64 + k1o);
    WAITLG(0); SB0();
    __builtin_amdgcn_s_setprio(1);
    #pragma unroll
    for (int f = 0; f < 4; f++)
      #pragma unroll
      for (int n = 0; n < 4; n++)
        acc[f][n] = __builtin_amdgcn_mfma_f32_16x16x32_bf16(af[f], wf[n], acc[f][n], 0, 0, 0);
    __builtin_amdgcn_s_setprio(0);
    // ---- phase 3: (mh1, kh1) ----
    #pragma unroll
    for (int f = 0; f < 4; f++)
      af[f] = *(const bv8*)(Ab + (wr + 64 + f * 16 + lr) * 64 + k1o);
    WAITLG(0); SB0();
    __builtin_amdgcn_s_setprio(1);
    #pragma unroll
    for (int f = 0; f < 4; f++)
      #pragma unroll
      for (int n = 0; n < 4; n++)
        acc[4 + f][n] = __builtin_amdgcn_mfma_f32_16x16x32_bf16(af[f], wf[n], acc[4 + f][n], 0, 0, 0);
    __builtin_amdgcn_s_setprio(0);
    // ---- boundary: t+1's loads were issued >=2 phases ago ----
    if (st) WAITVM(0);
    BAR();
  }

  if (EPI == 3) {
    for (int c = tid; c < 4096; c += 512) {
      int rrow = c >> 5, c8 = c & 31;
      *(sv8*)(lds + (size_t)c * 8) =
          *(const sv8*)(exCz + (size_t)rrow * 768 + n0 + c8 * 8);
    }
    if (tid < 64) {
      int rrow = tid >> 5, c8 = tid & 31;
      *(sv8*)(lds + 32768 + (size_t)tid * 8) =
          *(const sv8*)(exAz + (size_t)(bx * 2 + rrow) * 768 + n0 + c8 * 8);
    }
    __syncthreads();
  }

  int lr4 = (lane >> 4) * 4, lc = lane & 15;
  #pragma unroll
  for (int fm = 0; fm < 8; fm++) {
    #pragma unroll
    for (int r = 0; r < 4; r++) {
      int row = m0 + wr + (fm >> 2) * 64 + (fm & 3) * 16 + lr4 + r;
      #pragma unroll
      for (int fn = 0; fn < 4; fn++) {
        int col = n0 + wc + fn * 16 + lc;
        float v = acc[fm][fn][r] + bias[col];
        if (EPI == 1) v = fmaxf(v, 0.f);
        if (EPI == 2) v += b2f(respz[(size_t)row * ldr + col]);
        if (EPI == 3) v += b2f(lds[32768 + (size_t)((row - m0) >> 7) * 256 + (col - n0)])
                         + b2f(lds[(size_t)(row & 127) * 256 + (col - n0)]);
        outz[(size_t)row * ldo + col] = f2b(v);
      }
    }
  }
}

// ---------------- encoder self-attention (per q-row, per b,h) ----------------
__global__ __launch_bounds__(128) void enc_att(
    const u16* __restrict__ QKV, const int* __restrict__ encpad, u16* __restrict__ AO) {
  int s = blockIdx.x;
  int bh = blockIdx.y;
  int b = bh >> 1, h = bh & 1;
  int tid = threadIdx.x;
  __shared__ float q[384];
  __shared__ float sc[96];
  __shared__ float red[2];
  size_t rowq = ((size_t)b * 96 + s) * 2304;
  for (int d = tid; d < 384; d += 128) q[d] = b2f(QKV[rowq + h * 384 + d]);
  __syncthreads();
  if (tid < 96) {
    const u16* kr = QKV + ((size_t)b * 96 + tid) * 2304 + 768 + h * 384;
    float acc = 0.f;
    for (int d = 0; d < 384; d++) acc += q[d] * b2f(kr[d]);
    acc *= 0.05103103630798287f;
    if (encpad[b * 96 + tid]) acc = -1e9f;
    sc[tid] = acc;
  }
  __syncthreads();
  if (tid == 0) {
    float m = sc[0];
    for (int k = 1; k < 96; k++) m = fmaxf(m, sc[k]);
    red[0] = m;
  }
  __syncthreads();
  if (tid < 96) sc[tid] = __expf(sc[tid] - red[0]);
  __syncthreads();
  if (tid == 0) {
    float sum = 0.f;
    for (int k = 0; k < 96; k++) sum += sc[k];
    red[1] = 1.f / sum;
  }
  __syncthreads();
  float inv = red[1];
  for (int d = tid; d < 384; d += 128) {
    const u16* vb = QKV + (size_t)b * 96 * 2304 + 1536 + h * 384 + d;
    float acc = 0.f;
    for (int k = 0; k < 96; k++) acc += sc[k] * b2f(vb[(size_t)k * 2304]);
    AO[((size_t)b * 96 + s) * 768 + h * 384 + d] = f2b(acc * inv);
  }
}

// ---------------- decoder softmax (all batches; SA[i]+SC[j]+q0k) -------------
__global__ __launch_bounds__(256) void softmax_pairs(
    const float* __restrict__ SA, const float* __restrict__ SC,
    const float* __restrict__ q0k,
    const int* __restrict__ encpad, u16* __restrict__ P) {
  int wave = threadIdx.x >> 6, lane = threadIdx.x & 63;
  int bi = blockIdx.y;
  int p = blockIdx.x * 4 + wave;
  int i = p >> 7, j = p & 127;
  const float* sa = SA + ((size_t)bi * 128 + i) * 192;
  const float* sc = SC + ((size_t)bi * 128 + j) * 192;
  const float* qk = q0k + bi * 192;
  int c0 = lane * 3;
  float s0, s1, s2;
  {
    int c = c0;     int k = (c < 96) ? c : c - 96;
    s0 = encpad[bi * 96 + k] ? -1e9f : (sa[c] + sc[c] + qk[c]);
    c = c0 + 1;     k = (c < 96) ? c : c - 96;
    s1 = encpad[bi * 96 + k] ? -1e9f : (sa[c] + sc[c] + qk[c]);
    c = c0 + 2;     k = (c < 96) ? c : c - 96;
    s2 = encpad[bi * 96 + k] ? -1e9f : (sa[c] + sc[c] + qk[c]);
  }
  float m = fmaxf(s0, fmaxf(s1, s2));
  #pragma unroll
  for (int d = 1; d <= 16; d <<= 1) m = fmaxf(m, __shfl_xor(m, d));
  float e0 = __expf(s0 - m), e1 = __expf(s1 - m), e2 = __expf(s2 - m);
  float sum = e0 + e1 + e2;
  #pragma unroll
  for (int d = 1; d <= 16; d <<= 1) sum += __shfl_xor(sum, d);
  float inv = 1.f / sum;
  u16* o = P + ((size_t)bi * 16384 + p) * 192 + c0;
  o[0] = f2b(e0 * inv); o[1] = f2b(e1 * inv); o[2] = f2b(e2 * inv);
}

// ---------------- LayerNorm over rows of 768 (bf16, in-place safe) -----------
__global__ __launch_bounds__(256) void ln_rows(
    const u16* __restrict__ Y, const float* __restrict__ g,
    const float* __restrict__ bt, u16* __restrict__ X, int rows) {
  int wave = threadIdx.x >> 6, lane = threadIdx.x & 63;
  int row = blockIdx.x * 4 + wave;
  if (row >= rows) return;
  const u16* y = Y + (size_t)row * 768;
  sv8 v1 = *(const sv8*)(y + lane * 8);
  sv4 v2 = *(const sv4*)(y + 512 + lane * 4);
  float x[12];
  #pragma unroll
  for (int t = 0; t < 8; t++) x[t] = b2f((u16)v1[t]);
  #pragma unroll
  for (int t = 0; t < 4; t++) x[8 + t] = b2f((u16)v2[t]);
  float s = 0.f, q = 0.f;
  #pragma unroll
  for (int t = 0; t < 12; t++) { s += x[t]; q += x[t] * x[t]; }
  #pragma unroll
  for (int d = 1; d <= 32; d <<= 1) { s += __shfl_xor(s, d); q += __shfl_xor(q, d); }
  float mean = s * (1.f / 768.f);
  float var = q * (1.f / 768.f) - mean * mean;
  float rstd = rsqrtf(var + 1e-5f);
  u16* xo = X + (size_t)row * 768;
  sv8 w1; sv4 w2;
  #pragma unroll
  for (int t = 0; t < 8; t++) {
    int c = lane * 8 + t;
    w1[t] = (short)f2b((x[t] - mean) * rstd * g[c] + bt[c]);
  }
  #pragma unroll
  for (int t = 0; t < 4; t++) {
    int c = 512 + lane * 4 + t;
    w2[t] = (short)f2b((x[8 + t] - mean) * rstd * g[c] + bt[c]);
  }
  *(sv8*)(xo + lane * 8) = w1;
  *(sv4*)(xo + 512 + lane * 4) = w2;
}

// ---------------- final fused LN + fc dot --------------------------------
__global__ __launch_bounds__(256) void final_rows(
    const u16* __restrict__ Y, const float* __restrict__ gfc,
    const float* __restrict__ scal, float* __restrict__ out, int rows) {
  int wave = threadIdx.x >> 6, lane = threadIdx.x & 63;
  int row = blockIdx.x * 4 + wave;
  if (row >= rows) return;
  const u16* y = Y + (size_t)row * 768;
  sv8 v1 = *(const sv8*)(y + lane * 8);
  sv4 v2 = *(const sv4*)(y + 512 + lane * 4);
  float x[12];
  #pragma unroll
  for (int t = 0; t < 8; t++) x[t] = b2f((u16)v1[t]);
  #pragma unroll
  for (int t = 0; t < 4; t++) x[8 + t] = b2f((u16)v2[t]);
  float s = 0.f, q = 0.f, sg = 0.f;
  #pragma unroll
  for (int t = 0; t < 8; t++) {
    int c = lane * 8 + t;
    s += x[t]; q += x[t] * x[t]; sg += x[t] * gfc[c];
  }
  #pragma unroll
  for (int t = 0; t < 4; t++) {
    int c = 512 + lane * 4 + t;
    s += x[8 + t]; q += x[8 + t] * x[8 + t]; sg += x[8 + t] * gfc[c];
  }
  #pragma unroll
  for (int d = 1; d <= 32; d <<= 1) {
    s += __shfl_xor(s, d); q += __shfl_xor(q, d); sg += __shfl_xor(sg, d);
  }
  float mean = s * (1.f / 768.f);
  float var = q * (1.f / 768.f) - mean * mean;
  float rstd = rsqrtf(var + 1e-5f);
  if (lane == 0) out[row] = rstd * (sg - mean * scal[1]) + scal[0];
}

// =============================== host ========================================
extern "C" void kernel_launch(void* const* d_in, const int* in_sizes, int n_in,
                              void* d_out, int out_size, void* d_ws, size_t ws_size,
                              hipStream_t stream) {
  (void)in_sizes; (void)n_in; (void)out_size;
  const float* hs        = (const float*)d_in[0];
  const float* logits    = (const float*)d_in[1];
  const int*   bmask     = (const int*)d_in[2];
  const float* W_rel     = (const float*)d_in[3];
  const float* b_rel     = (const float*)d_in[4];
  const float* enc_in_w  = (const float*)d_in[5];
  const float* enc_in_b  = (const float*)d_in[6];
  const float* enc_out_w = (const float*)d_in[7];
  const float* enc_out_b = (const float*)d_in[8];
  const float* enc_l1_w  = (const float*)d_in[9];
  const float* enc_l1_b  = (const float*)d_in[10];
  const float* enc_l2_w  = (const float*)d_in[11];
  const float* enc_l2_b  = (const float*)d_in[12];
  const float* enc_ln1_g = (const float*)d_in[13];
  const float* enc_ln1_b = (const float*)d_in[14];
  const float* enc_ln2_g = (const float*)d_in[15];
  const float* enc_ln2_b = (const float*)d_in[16];
  const float* dec_in_w  = (const float*)d_in[17];
  const float* dec_in_b  = (const float*)d_in[18];
  const float* dec_out_w = (const float*)d_in[19];
  const float* dec_out_b = (const float*)d_in[20];
  const float* dec_l1_w  = (const float*)d_in[21];
  const float* dec_l1_b  = (const float*)d_in[22];
  const float* dec_l2_w  = (const float*)d_in[23];
  const float* dec_l2_b  = (const float*)d_in[24];
  const float* dec_ln1_g = (const float*)d_in[25];
  const float* dec_ln1_b = (const float*)d_in[26];
  const float* dec_ln2_g = (const float*)d_in[27];
  const float* dec_ln2_b = (const float*)d_in[28];
  const float* fc_w      = (const float*)d_in[29];
  const float* fc_b      = (const float*)d_in[30];

  char* base = (char*)d_ws;
  size_t off = 0;
  auto alloc = [&](size_t bytes) -> void* {
    size_t o = (off + 255) & ~(size_t)255;
    off = o + bytes;
    return (void*)(base + o);
  };

  u16* hsb   = (u16*)alloc((size_t)393216 * 2);
  u16* wrelb = (u16*)alloc((size_t)1179648 * 2);
  u16* eiwb  = (u16*)alloc((size_t)1769472 * 2);
  u16* eowb  = (u16*)alloc((size_t)589824 * 2);
  u16* el1b  = (u16*)alloc((size_t)589824 * 2);
  u16* el2b  = (u16*)alloc((size_t)589824 * 2);
  u16* diwb  = (u16*)alloc((size_t)1769472 * 2);
  u16* dowb  = (u16*)alloc((size_t)589824 * 2);
  u16* dl1b  = (u16*)alloc((size_t)589824 * 2);
  u16* dl2b  = (u16*)alloc((size_t)589824 * 2);
  float* Af  = (float*)alloc((size_t)786432 * 4);
  float* Cf  = Af + 393216;
  u16* ACb   = (u16*)alloc((size_t)786432 * 2);
  float* q0  = (float*)alloc(768 * 4);
  float* q0k = (float*)alloc(768 * 4);
  float* bbv = (float*)alloc(768 * 4);
  float* gfc = (float*)alloc(768 * 4);
  float* scal = (float*)alloc(4 * 4);
  int* idxb   = (int*)alloc(384 * 4);
  int* encpadb = (int*)alloc(384 * 4);
  int* zflagb  = (int*)alloc(384 * 4);
  u16* PPb   = (u16*)alloc((size_t)294912 * 2);
  u16* QKVe  = (u16*)alloc((size_t)884736 * 2);
  u16* AOe   = (u16*)alloc((size_t)294912 * 2);
  u16* Ye    = (u16*)alloc((size_t)294912 * 2);
  u16* Xe    = (u16*)alloc((size_t)294912 * 2);
  u16* He    = (u16*)alloc((size_t)294912 * 2);
  u16* Y2e   = (u16*)alloc((size_t)294912 * 2);
  u16* patternsb = (u16*)alloc((size_t)294912 * 2);
  u16* khb   = (u16*)alloc((size_t)294912 * 2);
  u16* vhb   = (u16*)alloc((size_t)294912 * 2);
  u16* AqCqb = (u16*)alloc((size_t)786432 * 2);
  float* SASCf = (float*)alloc((size_t)196608 * 4);
  u16* VOTb  = (u16*)alloc((size_t)589824 * 2);
  u16* Pb    = (u16*)alloc((size_t)12582912 * 2);   // 4 x 16384 x 192

  const size_t ACT1 = (size_t)12582912 * 2;
  size_t fixed = (off + 255) & ~(size_t)255;
  int NB = 1;
  if (fixed + 2 * 4 * ACT1 + 4096 <= ws_size) NB = 4;
  else if (fixed + 2 * 2 * ACT1 + 4096 <= ws_size) NB = 2;
  u16* Y1buf = (u16*)alloc((size_t)NB * 12582912 * 2);
  u16* H1buf = (u16*)alloc((size_t)NB * 12582912 * 2);

  CvtArgs ca{};
  int ci = 0;
  auto addc = [&](const float* s, u16* d, int n) { ca.src[ci] = s; ca.dst[ci] = d; ca.n[ci] = n; ci++; };
  addc(hs, hsb, 393216);        addc(W_rel, wrelb, 1179648);
  addc(enc_in_w, eiwb, 1769472); addc(enc_out_w, eowb, 589824);
  addc(enc_l1_w, el1b, 589824);  addc(enc_l2_w, el2b, 589824);
  addc(dec_in_w, diwb, 1769472); addc(dec_out_w, dowb, 589824);
  addc(dec_l1_w, dl1b, 589824);  addc(dec_l2_w, dl2b, 589824);
  cvt_multi<<<dim3(1728, 10, 1), 256, 0, stream>>>(ca);

  prep_q0<<<192, 256, 0, stream>>>(dec_in_w, dec_in_b, b_rel, q0);
  prep_misc<<<1, 256, 0, stream>>>(dec_out_b, b_rel, dec_ln2_g, dec_ln2_b, fc_w, fc_b,
                                   bbv, gfc, scal);
  select_pairs<<<dim3(4, 1, 1), 256, 0, stream>>>(logits, bmask, idxb, encpadb, zflagb);

  gemm_bt<0, 2, 64><<<dim3(8, 12, 2), 256, 0, stream>>>(hsb, wrelb, nullptr, Af, ACb,
      nullptr, 0, 512, 768, 768, 768, 1536, 768,
      1, -1, 0, 0, 0, 768, 0, 393216, 0, 1.f);

  gather_pp<<<dim3(96, 4, 1), 256, 0, stream>>>(Af, Cf, b_rel, idxb, zflagb, PPb);

  gemm_bt<0, 0, 64><<<dim3(6, 36, 1), 256, 0, stream>>>(PPb, eiwb, enc_in_b, QKVe, nullptr,
      nullptr, 0, 384, 2304, 768, 768, 768, 2304,
      1, -1, 0, 0, 0, 0, 0, 0, 0, 1.f);
  enc_att<<<dim3(96, 8, 1), 128, 0, stream>>>(QKVe, encpadb, AOe);
  gemm_bt<2, 0, 64><<<dim3(6, 12, 1), 256, 0, stream>>>(AOe, eowb, enc_out_b, Ye, nullptr,
      PPb, 768, 384, 768, 768, 768, 768, 768,
      1, -1, 0, 0, 0, 0, 0, 0, 0, 1.f);
  ln_rows<<<96, 256, 0, stream>>>(Ye, enc_ln1_g, enc_ln1_b, Xe, 384);
  gemm_bt<1, 0, 64><<<dim3(6, 12, 1), 256, 0, stream>>>(Xe, el1b, enc_l1_b, He, nullptr,
      nullptr, 0, 384, 768, 768, 768, 768, 768,
      1, -1, 0, 0, 0, 0, 0, 0, 0, 1.f);
  gemm_bt<2, 0, 64><<<dim3(6, 12, 1), 256, 0, stream>>>(He, el2b, enc_l2_b, Y2e, nullptr,
      Xe, 768, 384, 768, 768, 768, 768, 768,
      1, -1, 0, 0, 0, 0, 0, 0, 0, 1.f);
  ln_rows<<<96, 256, 0, stream>>>(Y2e, enc_ln2_g, enc_ln2_b, patternsb, 384);

  gemm_bt<0, 0, 64><<<dim3(6, 12, 2), 256, 0, stream>>>(patternsb, diwb + (size_t)768 * 768,
      dec_in_b + 768, khb, nullptr, nullptr, 0,
      384, 768, 768, 768, 768, 768,
      1, -1, 768, 0, 0, 589824, 0, 294912, 0, 1.f);
  prep_q0k<<<192, 256, 0, stream>>>(q0, khb, q0k);
  gemm_bt<0, 0, 64><<<dim3(16, 12, 1), 256, 0, stream>>>(ACb, diwb, nullptr, AqCqb, nullptr,
      nullptr, 0, 1024, 768, 768, 768, 768, 768,
      1, -1, 0, 0, 0, 0, 0, 0, 0, 1.f);
  const float scl = 0.05103103630798287f; // 1/sqrt(384)
  gemm_bt<0, 1, 64><<<dim3(2, 2, 16), 256, 0, stream>>>(AqCqb, khb, nullptr, SASCf, nullptr,
      nullptr, 0, 128, 96, 384, 768, 768, 192,
      2, 3, 0, 98304, 384, 73728, 384, 24576, 96, scl);
  gemm_bt<0, 0, 64><<<dim3(12, 2, 8), 256, 0, stream>>>(dowb, vhb, nullptr, VOTb, nullptr,
      nullptr, 0, 768, 96, 384, 768, 768, 192,
      2, -1, 0, 0, 384, 73728, 384, 147456, 96, 1.f);

  softmax_pairs<<<dim3(4096, 4), 256, 0, stream>>>(SASCf, SASCf + 98304, q0k, encpadb, Pb);
  const long PB_B = 3145728, VOT_B = 147456, ACT_B = 12582912;
  const long EXU_B = 98304;
  for (int g = 0; g < 4; g += NB) {
    gemm256<3><<<dim3(64, 3, NB), 512, 0, stream>>>(
        Pb + (size_t)g * PB_B, VOTb + (size_t)g * VOT_B, bbv, Y1buf,
        Y1buf, 0,
        ACb + (size_t)g * EXU_B,
        ACb + 393216 + (size_t)g * EXU_B,
        192, 192, 192, 768, PB_B, VOT_B, ACT_B, 0, EXU_B);
    ln_rows<<<NB * 4096, 256, 0, stream>>>(Y1buf, dec_ln1_g, dec_ln1_b, Y1buf, NB * 16384);
    gemm256<1><<<dim3(64, 3, NB), 512, 0, stream>>>(
        Y1buf, dl1b, dec_l1_b, H1buf, H1buf, 0, ACb, ACb,
        768, 768, 768, 768, ACT_B, 0, ACT_B, 0, 0);
    gemm256<2><<<dim3(64, 3, NB), 512, 0, stream>>>(
        H1buf, dl2b, dec_l2_b, Y1buf, Y1buf, 768, ACb, ACb,
        768, 768, 768, 768, ACT_B, 0, ACT_B, ACT_B, 0);
    final_rows<<<NB * 4096, 256, 0, stream>>>(Y1buf, gfc, scal,
        (float*)d_out + (size_t)g * 16384, NB * 16384);
  }
}